// Round 21
// baseline (487.353 us; speedup 1.0000x reference)
//
#include <hip/hip_runtime.h>
#include <hip/hip_bf16.h>
#include <cstdint>

typedef unsigned short u16;
typedef unsigned int u32;
typedef __attribute__((ext_vector_type(8))) short short8;
typedef __attribute__((ext_vector_type(4))) float f32x4;

#define NB 8
#define NS 2048
#define ND 512
#define NM (NB * NS)            // 16384 rows
#define CL 64                   // tril-G tile length
#define NCH (NS / CL)           // 32 tril tiles
#define CL2 128                 // recurrence chunk length
#define NCH2 (NS / CL2)         // 16 chunks
static constexpr size_t BSDn = (size_t)NM * ND;   // 8388608 elems
#define KSCALE 0.044194173824159216f              // 1/sqrt(512)

// U-region byte offsets
#define OFF_QB ((size_t)0)            // Qbf  [b,t,d] bf16 16MB
#define OFF_KB (BSDn * 2)             // Kbf  [b,t,d] (gqk); then A1 tiles (gates)
#define OFF_KT (BSDn * 4)             // KT   [b,d,t] bf16 (scaled) 16MB
#define OFF_VT (BSDn * 6)             // VT   [b,d,t] bf16 16MB
#define OFF_OT (BSDn * 8)             // OT   [b,d,t] bf16 (sigmoid) 16MB
#define OFF_IT (BSDn * 10)            // IT   [b,d,t] bf16 16MB (dead after gates)
#define OFF_FT (BSDn * 14)            // FT   [b,d,t] f32 32MB (dead after gates)
#define OFF_G  (BSDn * 18)            // Gd   [b][32][64][64] bf16 2MB (tril diag)
#define OFF_GO (BSDn * 18 + ((size_t)2 << 20))   // Goff [b][16][64][64] 1MB
#define OFF_AC (BSDn * 18 + ((size_t)3 << 20))   // Acorr (32MB) / Hbuf(bf16) alias
#define OFF_X  (OFF_AC + ((size_t)32 << 20))     // A2 (16MB)
#define OFF_UB (OFF_X + ((size_t)16 << 20))      // Ub (16MB)
#define OFF_GA (OFF_UB + ((size_t)16 << 20))     // gam (f32)
#define OFF_END (OFF_GA + ((size_t)1 << 20))

typedef __attribute__((address_space(1))) const u32 gas_u32;
typedef __attribute__((address_space(3))) u32 las_u32;

__device__ __forceinline__ u16 f2bf(float f) {
    u32 i = __builtin_bit_cast(u32, f);
    u32 r = i + 0x7FFFu + ((i >> 16) & 1u);
    return (u16)(r >> 16);
}
__device__ __forceinline__ float bf2f(u16 h) {
    return __builtin_bit_cast(float, (u32)h << 16);
}
__device__ __forceinline__ float bflo(u32 w) {
    return __builtin_bit_cast(float, w << 16);
}
__device__ __forceinline__ float bfhi(u32 w) {
    return __builtin_bit_cast(float, w & 0xffff0000u);
}

// LDS-only barrier: drains own LDS ops + s_barrier; global prefetch loads
// stay in flight across the barrier.
__device__ __forceinline__ void lds_barrier() {
    __builtin_amdgcn_sched_barrier(0);
    asm volatile("s_waitcnt lgkmcnt(0)" ::: "memory");
    __builtin_amdgcn_s_barrier();
    __builtin_amdgcn_sched_barrier(0);
}

// ---------------- fused prep: W5T, WcT (ft), W1T, W2T, bias concat, LN1
__global__ __launch_bounds__(256) void prep_kernel(
        const float* __restrict__ Wq, const float* __restrict__ Wk,
        const float* __restrict__ Wv, const float* __restrict__ Wo,
        const float* __restrict__ Wi, const float* __restrict__ Wf,
        const float* __restrict__ W1, const float* __restrict__ W2,
        const float* __restrict__ bq, const float* __restrict__ bk,
        const float* __restrict__ bv, const float* __restrict__ bo,
        const float* __restrict__ bi, const float* __restrict__ bf_,
        const float* __restrict__ x, const float* __restrict__ ln1g,
        const float* __restrict__ ln1b,
        u16* __restrict__ W5T, u16* __restrict__ WcT,
        u16* __restrict__ W1T, u16* __restrict__ W2T,
        float* __restrict__ ball, u16* __restrict__ nout) {
    int blk = blockIdx.x, tid = threadIdx.x;
    if (blk < 5120) {                          // W5T [2560][512]: q,k,v,o,it
        int idx = blk * 256 + tid;
        int n = idx >> 9, k = idx & 511;
        int p = n >> 9, d = n & 511;
        const float* Wp = (p == 0) ? Wq : (p == 1) ? Wk : (p == 2) ? Wv
                        : (p == 3) ? Wo : Wi;
        W5T[idx] = f2bf(Wp[(size_t)k * 512 + d]);
    } else if (blk < 8192) {                   // WcT [512][1536] = [WH|WH|WL] (ft)
        int idx = (blk - 5120) * 256 + tid;
        int n = idx / 1536, k = idx - n * 1536;
        int d = n;
        u16 o;
        if (k < 1024) {
            o = f2bf(Wf[(size_t)(k & 511) * 512 + d]);
        } else {
            float w = Wf[(size_t)(k - 1024) * 512 + d];
            o = f2bf(w - bf2f(f2bf(w)));
        }
        WcT[idx] = o;
    } else if (blk < 12288) {                  // W1T [2048][512]
        int idx = (blk - 8192) * 256 + tid;
        int n = idx >> 9, k = idx & 511;
        W1T[idx] = f2bf(W1[(size_t)k * 2048 + n]);
    } else if (blk < 16384) {                  // W2T [512][2048]
        int idx = (blk - 12288) * 256 + tid;
        int n = idx >> 11, k = idx & 2047;
        W2T[idx] = f2bf(W2[(size_t)k * 512 + n]);
    } else if (blk < 16396) {                  // bias concat [q,k,v,o,it,ft]
        int idx = (blk - 16384) * 256 + tid;
        if (idx < 3072) {
            int p = idx >> 9, d = idx & 511;
            float v;
            switch (p) {
                case 0: v = bq[d]; break;
                case 1: v = bk[d]; break;
                case 2: v = bv[d]; break;
                case 3: v = bo[d]; break;
                case 4: v = bi[d]; break;
                default: v = bf_[d]; break;
            }
            ball[idx] = v;
        }
    } else {                                   // LN1: 4 rows per block
        int wave = tid >> 6, lane = tid & 63;
        size_t row = (size_t)(blk - 16396) * 4 + wave;
        const float* xr = x + row * ND + lane * 8;
        float4 a0 = *(const float4*)xr;
        float4 a1 = *(const float4*)(xr + 4);
        float xs[8] = {a0.x, a0.y, a0.z, a0.w, a1.x, a1.y, a1.z, a1.w};
        float s = 0.f;
#pragma unroll
        for (int u = 0; u < 8; ++u) s += xs[u];
#pragma unroll
        for (int off = 32; off; off >>= 1) s += __shfl_xor(s, off);
        float mu = s * (1.0f / ND);
        float ss = 0.f;
#pragma unroll
        for (int u = 0; u < 8; ++u) { xs[u] -= mu; ss += xs[u] * xs[u]; }
#pragma unroll
        for (int off = 32; off; off >>= 1) ss += __shfl_xor(ss, off);
        float rs = rsqrtf(ss * (1.0f / ND) + 1e-5f);
        const float* gp = ln1g + lane * 8;
        const float* bp = ln1b + lane * 8;
        float4 g0 = *(const float4*)gp, g1 = *(const float4*)(gp + 4);
        float4 c0 = *(const float4*)bp, c1 = *(const float4*)(bp + 4);
        float gg[8] = {g0.x, g0.y, g0.z, g0.w, g1.x, g1.y, g1.z, g1.w};
        float cc[8] = {c0.x, c0.y, c0.z, c0.w, c1.x, c1.y, c1.z, c1.w};
        u32 owh[4], owl[4];
#pragma unroll
        for (int u = 0; u < 4; ++u) {
            float y0 = xs[2 * u] * rs * gg[2 * u] + cc[2 * u];
            float y1 = xs[2 * u + 1] * rs * gg[2 * u + 1] + cc[2 * u + 1];
            u16 h0 = f2bf(y0), h1 = f2bf(y1);
            u16 l0 = f2bf(y0 - bf2f(h0)), l1 = f2bf(y1 - bf2f(h1));
            owh[u] = (u32)h0 | ((u32)h1 << 16);
            owl[u] = (u32)l0 | ((u32)l1 << 16);
        }
        u16* rb = nout + row * 1024;
        *(uint4*)(rb + lane * 8) = make_uint4(owh[0], owh[1], owh[2], owh[3]);
        *(uint4*)(rb + 512 + lane * 8) = make_uint4(owl[0], owl[1], owl[2], owl[3]);
    }
}

// ---------------- residual add + LN2 (h in bf16)
__global__ __launch_bounds__(256) void resid_ln2_kernel(const float* __restrict__ x,
        const u16* __restrict__ h, const float* __restrict__ g,
        const float* __restrict__ bb, float* __restrict__ outb,
        u16* __restrict__ fin) {
    int wave = threadIdx.x >> 6, lane = threadIdx.x & 63;
    size_t row = (size_t)blockIdx.x * 4 + wave;
    const float* xr = x + row * ND + lane * 8;
    float4 a0 = *(const float4*)xr;
    float4 a1 = *(const float4*)(xr + 4);
    uint4 hv = *(const uint4*)(h + row * ND + lane * 8);
    float xs[8] = {a0.x + bflo(hv.x), a0.y + bfhi(hv.x),
                   a0.z + bflo(hv.y), a0.w + bfhi(hv.y),
                   a1.x + bflo(hv.z), a1.y + bfhi(hv.z),
                   a1.z + bflo(hv.w), a1.w + bfhi(hv.w)};
    float* orow = outb + row * ND + lane * 8;
    *(float4*)orow = make_float4(xs[0], xs[1], xs[2], xs[3]);
    *(float4*)(orow + 4) = make_float4(xs[4], xs[5], xs[6], xs[7]);
    float s = 0.f;
#pragma unroll
    for (int u = 0; u < 8; ++u) s += xs[u];
#pragma unroll
    for (int off = 32; off; off >>= 1) s += __shfl_xor(s, off);
    float mu = s * (1.0f / ND);
    float ss = 0.f;
#pragma unroll
    for (int u = 0; u < 8; ++u) { xs[u] -= mu; ss += xs[u] * xs[u]; }
#pragma unroll
    for (int off = 32; off; off >>= 1) ss += __shfl_xor(ss, off);
    float rs = rsqrtf(ss * (1.0f / ND) + 1e-5f);
    const float* gp = g + lane * 8;
    const float* bp = bb + lane * 8;
    float4 g0 = *(const float4*)gp, g1 = *(const float4*)(gp + 4);
    float4 c0 = *(const float4*)bp, c1 = *(const float4*)(bp + 4);
    float gg[8] = {g0.x, g0.y, g0.z, g0.w, g1.x, g1.y, g1.z, g1.w};
    float cc[8] = {c0.x, c0.y, c0.z, c0.w, c1.x, c1.y, c1.z, c1.w};
    u32 ow[4];
#pragma unroll
    for (int u = 0; u < 4; ++u) {
        float y0 = xs[2 * u] * rs * gg[2 * u] + cc[2 * u];
        float y1 = xs[2 * u + 1] * rs * gg[2 * u + 1] + cc[2 * u + 1];
        ow[u] = (u32)f2bf(y0) | ((u32)f2bf(y1) << 16);
    }
    *(uint4*)(fin + row * ND + lane * 8) = make_uint4(ow[0], ow[1], ow[2], ow[3]);
}

// ---------------- fused G kernel: diag (tril, 256 blocks) + off-diag (128 blocks)
__global__ __launch_bounds__(256) void gqk2_kernel(
        const u16* __restrict__ Qb, const u16* __restrict__ Kb,
        u16* __restrict__ Gd, u16* __restrict__ Go) {
    __shared__ u16 Qs[64][520];
    __shared__ u16 Ks[64][520];
    int tid = threadIdx.x;
    int w = tid >> 6, lane = tid & 63;
    int blk = blockIdx.x;
    int b, t0q, t0k;
    bool masked;
    u16* gout;
    if (blk < 256) {
        b = blk >> 5;
        int c = blk & 31;
        t0q = t0k = c * CL;
        masked = true;
        gout = Gd + (size_t)(b * NCH + c) * CL * CL;
    } else {
        int z = blk - 256;
        b = z >> 4;
        int c = z & 15;
        t0q = c * CL2 + 64;
        t0k = c * CL2;
        masked = false;
        gout = Go + (size_t)(b * NCH2 + c) * CL * CL;
    }
    {
        int row = tid >> 2, cb = (tid & 3) * 128;
        const u16* qsrc = Qb + ((size_t)b * NS + t0q + row) * ND + cb;
        const u16* ksrc = Kb + ((size_t)b * NS + t0k + row) * ND + cb;
#pragma unroll
        for (int u = 0; u < 16; ++u) {
            *(short8*)&Qs[row][cb + u * 8] = *(const short8*)(qsrc + u * 8);
            *(short8*)&Ks[row][cb + u * 8] = *(const short8*)(ksrc + u * 8);
        }
    }
    __syncthreads();
    int qw = lane & 15, kg = lane >> 4;
    f32x4 ga[4];
#pragma unroll
    for (int ns = 0; ns < 4; ++ns) ga[ns] = (f32x4){0.f, 0.f, 0.f, 0.f};
    for (int kb = 0; kb < 16; ++kb) {
        short8 aq = *(const short8*)&Qs[(w << 4) + qw][kb * 32 + (kg << 3)];
#pragma unroll
        for (int ns = 0; ns < 4; ++ns) {
            short8 bk = *(const short8*)&Ks[(ns << 4) + qw][kb * 32 + (kg << 3)];
            ga[ns] = __builtin_amdgcn_mfma_f32_16x16x32_bf16(aq, bk, ga[ns], 0, 0, 0);
        }
    }
#pragma unroll
    for (int ns = 0; ns < 4; ++ns) {
#pragma unroll
        for (int rg = 0; rg < 4; ++rg) {
            int t = (w << 4) + (kg << 2) + rg;
            int s = (ns << 4) + qw;
            gout[t * CL + s] = (!masked || s <= t) ? f2bf(ga[ns][rg]) : (u16)0;
        }
    }
}

// ---------------- gates kernel, CL2=128 (IT bf16)
__global__ __launch_bounds__(128) void gates_kernel(
        const u16* __restrict__ IT, const float* __restrict__ FT,
        const u16* __restrict__ VT,
        u16* __restrict__ A1g, u16* __restrict__ A2g,
        u16* __restrict__ Ubg, float* __restrict__ gamg) {
    int w = threadIdx.x >> 6, lane = threadIdx.x & 63;
    int rp = blockIdx.x & 7;
    int bl = blockIdx.x >> 3;            // b*32 + isl
    int b = bl >> 5, isl = bl & 31;
    int il = rp * 2 + w;                 // 0..15
    int i = (isl << 4) + il;
    size_t rowb = ((size_t)b * ND + i) * NS;
    size_t tb = (size_t)bl * 32768 + il * 128;   // + c*2048 + t
    float mo = 0.f;
    for (int c = 0; c < NCH2; ++c) {
        size_t g0 = rowb + c * CL2 + lane;
        float ft0 = FT[g0], it0 = bf2f(IT[g0]), v0 = bf2f(VT[g0]);
        float ft1 = FT[g0 + 64], it1 = bf2f(IT[g0 + 64]), v1 = bf2f(VT[g0 + 64]);
        float bs0 = ft0;
#pragma unroll
        for (int o = 1; o < 64; o <<= 1) {
            float nv = __shfl_up(bs0, o);
            if (lane >= o) bs0 += nv;
        }
        float e0 = it0 - bs0;
        float M0 = e0;
#pragma unroll
        for (int o = 1; o < 64; o <<= 1) {
            float nv = __shfl_up(M0, o);
            if (lane >= o) M0 = fmaxf(M0, nv);
        }
        M0 = fmaxf(M0, mo);
        float M0t = __shfl(M0, 63);
        float bs0t = __shfl(bs0, 63);
        float bs1 = ft1;
#pragma unroll
        for (int o = 1; o < 64; o <<= 1) {
            float nv = __shfl_up(bs1, o);
            if (lane >= o) bs1 += nv;
        }
        bs1 += bs0t;
        float e1 = it1 - bs1;
        float M1 = e1;
#pragma unroll
        for (int o = 1; o < 64; o <<= 1) {
            float nv = __shfl_up(M1, o);
            if (lane >= o) M1 = fmaxf(M1, nv);
        }
        M1 = fmaxf(M1, M0t);
        float E = __shfl(M1, 63);
        float bst = __shfl(bs1, 63);
        size_t oofs = tb + (size_t)c * 2048 + lane;
        Ubg[oofs] = f2bf(__expf(e0 - E) * v0);
        A1g[oofs] = f2bf(__expf(mo - M0));
        A2g[oofs] = f2bf(__expf(fminf(E - M0, 80.f)));
        Ubg[oofs + 64] = f2bf(__expf(e1 - E) * v1);
        A1g[oofs + 64] = f2bf(__expf(mo - M1));
        A2g[oofs + 64] = f2bf(__expf(fminf(E - M1, 80.f)));
        if (lane == 0) gamg[((size_t)bl * NCH2 + c) * 16 + il] = __expf(mo - E);
        mo = bst + E;
    }
}

// ---------------- chunked mLSTM recurrence v6 (frozen at ~141us)
__global__ __launch_bounds__(512, 2) void recur_kernel(
        const u16* __restrict__ Qb, const u16* __restrict__ KT,
        const u16* __restrict__ Gd, const u16* __restrict__ Go,
        const u16* __restrict__ A1g, const u16* __restrict__ A2g,
        const u16* __restrict__ Ubg, const float* __restrict__ gamg,
        const u16* __restrict__ OT, u16* __restrict__ H) {
    __shared__ u16 Chi[2][16][520];
    __shared__ u16 Ubl[2][16][136];
    __shared__ u16 A1l[2][16][136];
    __shared__ u16 A2l[2][16][136];
    __shared__ float gaml[2][16];
    int tid = threadIdx.x;
    int w = tid >> 6, lane = tid & 63;
    int hb = w >> 2, tl16 = w & 3;
    int b = blockIdx.x & 7;              // XCD pin
    int isl = blockIdx.x >> 3;
    int i0 = isl << 4;
    int qw = lane & 15, kg = lane >> 4;
    f32x4 cacc[4];
#pragma unroll
    for (int n = 0; n < 4; ++n) cacc[n] = (f32x4){0.f, 0.f, 0.f, 0.f};

    size_t bT = (size_t)b * NS;
    size_t bD = (size_t)b * ND;
    size_t gt2 = (size_t)(b * 32 + isl) * 32768;
    int grow = tid >> 5;
    int gquad = (tid & 31) << 2;

    const u16* qpf = Qb + (bT + w * 16 + qw) * ND + (kg << 3);
    const u16* kpf = KT + (bD + w * 64 + qw) * NS + (kg << 3);
    const u16* gdp = Gd + ((size_t)(b * 32 + hb) * 4096)
                     + (size_t)(tl16 * 16 + qw) * 64 + (kg << 3);
    const u16* gop = Go + ((size_t)(b * 16) * 4096)
                     + (size_t)(tl16 * 16 + qw) * 64 + (kg << 3);
    const u16* ubp = Ubg + gt2 + grow * 128 + gquad;
    const u16* a1p = A1g + gt2 + grow * 128 + gquad;
    const u16* a2p = A2g + gt2 + grow * 128 + gquad;
    const float* gamp = gamg + (size_t)(b * 32 + isl) * (NCH2 * 16) + tid;
    const u16* otp = OT + (bD + i0 + qw) * NS + w * 16 + (kg << 2);

    uint2 nub = make_uint2(0, 0), na1 = make_uint2(0, 0), na2 = make_uint2(0, 0);
    float ngam = 0.f;
    auto issue_gates = [&]() {
        nub = *(const uint2*)ubp; ubp += 2048;
        na1 = *(const uint2*)a1p; a1p += 2048;
        na2 = *(const uint2*)a2p; a2p += 2048;
        if (tid < 16) ngam = *gamp;
        gamp += 16;
    };
    issue_gates();

    for (int c = 0; c < NCH2; ++c) {
        int buf = c & 1;
        int t0 = c * CL2;
        short8 nq[16], nk[16], ngd[2], ngo[2];
#pragma unroll
        for (int kk = 0; kk < 16; ++kk) nq[kk] = *(const short8*)(qpf + kk * 32);
        qpf += CL2 * ND;
#pragma unroll
        for (int kb = 0; kb < 4; ++kb)
#pragma unroll
            for (int n = 0; n < 4; ++n)
                nk[kb * 4 + n] = *(const short8*)(kpf + (size_t)(n << 4) * NS + kb * 32);
        kpf += CL2;
        ngd[0] = *(const short8*)gdp;
        ngd[1] = *(const short8*)(gdp + 32);
        gdp += 2 * 4096;
        if (hb == 1) {
            ngo[0] = *(const short8*)gop;
            ngo[1] = *(const short8*)(gop + 32);
        }
        gop += 4096;
        uint2 cov = *(const uint2*)otp;
        otp += CL2;
        uint2 cub = nub, ca1 = na1, ca2 = na2;
        float cgam = ngam;
        if (c + 1 < NCH2) issue_gates();

        *(uint2*)&Ubl[buf][grow][gquad] = cub;
        *(uint2*)&A1l[buf][grow][gquad] = ca1;
        *(uint2*)&A2l[buf][grow][gquad] = ca2;
        if (tid < 16) gaml[buf][tid] = cgam;
#pragma unroll
        for (int n = 0; n < 4; ++n) {
            int j = (w << 6) + (n << 4) + qw;
#pragma unroll
            for (int rg = 0; rg < 4; ++rg)
                Chi[buf][(kg << 2) + rg][j] = f2bf(cacc[n][rg]);
        }
        lds_barrier();

        f32x4 qc0 = (f32x4){0.f, 0.f, 0.f, 0.f};
        f32x4 qc1 = (f32x4){0.f, 0.f, 0.f, 0.f};
#pragma unroll
        for (int kk = 0; kk < 8; ++kk) {
            short8 b0 = *(const short8*)&Chi[buf][qw][(2 * kk) * 32 + (kg << 3)];
            short8 b1_ = *(const short8*)&Chi[buf][qw][(2 * kk + 1) * 32 + (kg << 3)];
            qc0 = __builtin_amdgcn_mfma_f32_16x16x32_bf16(nq[2 * kk], b0, qc0, 0, 0, 0);
            qc1 = __builtin_amdgcn_mfma_f32_16x16x32_bf16(nq[2 * kk + 1], b1_, qc1, 0, 0, 0);
        }
        f32x4 pin = (f32x4){0.f, 0.f, 0.f, 0.f};
        if (hb == 0) {
#pragma unroll
            for (int kb = 0; kb < 2; ++kb) {
                short8 bu = *(const short8*)&Ubl[buf][qw][kb * 32 + (kg << 3)];
                pin = __builtin_amdgcn_mfma_f32_16x16x32_bf16(ngd[kb], bu, pin, 0, 0, 0);
            }
        } else {
#pragma unroll
            for (int kb = 0; kb < 2; ++kb) {
                short8 bu = *(const short8*)&Ubl[buf][qw][kb * 32 + (kg << 3)];
                pin = __builtin_amdgcn_mfma_f32_16x16x32_bf16(ngo[kb], bu, pin, 0, 0, 0);
            }
#pragma unroll
            for (int kb = 0; kb < 2; ++kb) {
                short8 bu = *(const short8*)&Ubl[buf][qw][64 + kb * 32 + (kg << 3)];
                pin = __builtin_amdgcn_mfma_f32_16x16x32_bf16(ngd[kb], bu, pin, 0, 0, 0);
            }
        }
        {
            float g[4];
#pragma unroll
            for (int rg = 0; rg < 4; ++rg) g[rg] = gaml[buf][(kg << 2) + rg];
#pragma unroll
            for (int n = 0; n < 4; ++n) {
#pragma unroll
                for (int rg = 0; rg < 4; ++rg) cacc[n][rg] *= g[rg];
            }
#pragma unroll
            for (int kb = 0; kb < 4; ++kb) {
                short8 au = *(const short8*)&Ubl[buf][qw][kb * 32 + (kg << 3)];
#pragma unroll
                for (int n = 0; n < 4; ++n)
                    cacc[n] = __builtin_amdgcn_mfma_f32_16x16x32_bf16(
                            au, nk[kb * 4 + n], cacc[n], 0, 0, 0);
            }
        }
        {
            float ov[4];
            ov[0] = bf2f((u16)(cov.x & 0xffff));
            ov[1] = bf2f((u16)(cov.x >> 16));
            ov[2] = bf2f((u16)(cov.y & 0xffff));
            ov[3] = bf2f((u16)(cov.y >> 16));
#pragma unroll
            for (int rg = 0; rg < 4; ++rg) {
                int tl = w * 16 + (kg << 2) + rg;
                float a1v = bf2f(A1l[buf][qw][tl]);
                float a2v = bf2f(A2l[buf][qw][tl]);
                float qc = qc0[rg] + qc1[rg];
                H[(bT + t0 + tl) * ND + i0 + qw] =
                        f2bf(ov[rg] * (a1v * qc + a2v * pin[rg]));
            }
        }
    }
}

// ---------------- bf16 MFMA GEMM: 256x128 tile, 8 waves, 3-buffer LDS,
// counted vmcnt(3), raw barriers, XCD-chunked swizzle, setprio MFMA clusters.
// MODE 0: qkvo+it (N=2560)   MODE 3: ft (N=512)
// MODE 1: ffn1 gelu bf16     MODE 2: ffn2 + resid f32
template <int MODE>
__global__ __launch_bounds__(512) void gemm_kernel(
        const u16* __restrict__ A, const u16* __restrict__ BT,
        int M, int N, int K, int lda, int ldb, int kwrap, int nx,
        const float* __restrict__ bias,
        char* __restrict__ pb,
        float* __restrict__ outf, u16* __restrict__ outh,
        const float* __restrict__ resid) {
    __shared__ u16 As[3][256 * 32];
    __shared__ u16 Bs[3][128 * 32];
    int tid = threadIdx.x;
    int wave = tid >> 6, lane = tid & 63;
    int wm = wave >> 1, wn = wave & 1;     // 4 x 2 wave grid
    // XCD-chunked swizzle: each XCD owns 8 consecutive A-panels (ny=64, 8 XCDs)
    int xcd = blockIdx.x & 7;
    int slot = blockIdx.x >> 3;
    int by = xcd * 8 + slot / nx;
    int bx = slot - (slot / nx) * nx;
    int m0 = by * 256;
    int n0 = bx * 128;

    f32x4 acc[4][4];
#pragma unroll
    for (int fi = 0; fi < 4; ++fi)
#pragma unroll
        for (int fj = 0; fj < 4; ++fj)
            acc[fi][fj] = (f32x4){0.f, 0.f, 0.f, 0.f};

    // staging: A rows [wave*32,+32) via 2 gloads; B rows [wave*16,+16) via 1.
    int srow = lane >> 2;
    int slotl = lane & 3;
    int rA0 = wave * 32 + srow;
    int gsA0 = (slotl ^ ((rA0 >> 1) & 3)) << 3;
    int gsA1 = (slotl ^ (((rA0 + 16) >> 1) & 3)) << 3;
    int rB = wave * 16 + srow;
    int gsB = (slotl ^ ((rB >> 1) & 3)) << 3;
    const u16* Ag0 = A + (size_t)(m0 + rA0) * lda + gsA0;
    const u16* Ag1 = A + (size_t)(m0 + rA0 + 16) * lda + gsA1;
    const u16* Bg = BT + (size_t)(n0 + rB) * ldb + gsB;
    int wlA0 = wave * 32 * 32;
    int wlA1 = wlA0 + 16 * 32;
    int wlB = wave * 16 * 32;

    int fr = lane & 15, kb = lane >> 4;
    int sa[4], sb[4];
#pragma unroll
    for (int f = 0; f < 4; ++f) {
        int ra = wm * 64 + f * 16 + fr;
        int rb = wn * 64 + f * 16 + fr;
        sa[f] = ra * 32 + ((kb ^ ((ra >> 1) & 3)) << 3);
        sb[f] = rb * 32 + ((kb ^ ((rb >> 1) & 3)) << 3);
    }

    int nk = K >> 5;
    auto STAGE = [&](int t, int bufi) {
        int k0 = t << 5;
        int ak0 = k0 - (k0 >= kwrap ? kwrap : 0);
        __builtin_amdgcn_global_load_lds((gas_u32*)(Ag0 + ak0), (las_u32*)(&As[bufi][wlA0]), 16, 0, 0);
        __builtin_amdgcn_global_load_lds((gas_u32*)(Ag1 + ak0), (las_u32*)(&As[bufi][wlA1]), 16, 0, 0);
        __builtin_amdgcn_global_load_lds((gas_u32*)(Bg + k0), (las_u32*)(&Bs[bufi][wlB]), 16, 0, 0);
    };
    STAGE(0, 0);
    STAGE(1, 1);
    int cur = 0;
#pragma unroll 1
    for (int t = 0; t < nk; ++t) {
        __builtin_amdgcn_sched_barrier(0);
        if (t + 1 < nk) {
            asm volatile("s_waitcnt vmcnt(3)" ::: "memory");
        } else {
            asm volatile("s_waitcnt vmcnt(0)" ::: "memory");
        }
        __builtin_amdgcn_s_barrier();
        __builtin_amdgcn_sched_barrier(0);
        short8 fa[4], fb[4];
#pragma unroll
        for (int f = 0; f < 4; ++f)
            fa[f] = *(const short8*)(&As[cur][sa[f]]);
        fb[0] = *(const short8*)(&Bs[cur][sb[0]]);
        fb[1] = *(const short8*)(&Bs[cur][sb[1]]);
        if (t + 2 < nk) {
            int b2 = cur - 1;
            if (b2 < 0) b2 += 3;
            STAGE(t + 2, b2);
        }
        // cluster 1: 8 MFMAs on fb[0..1], setprio-boosted
        __builtin_amdgcn_s_setprio(1);
#pragma unroll
        for (int fi = 0; fi < 4; ++fi) {
            acc[fi][0] = __builtin_amdgcn_mfma_f32_16x16x32_bf16(
                    fa[fi], fb[0], acc[fi][0], 0, 0, 0);
            acc[fi][1] = __builtin_amdgcn_mfma_f32_16x16x32_bf16(
                    fa[fi], fb[1], acc[fi][1], 0, 0, 0);
        }
        __builtin_amdgcn_s_setprio(0);
        fb[2] = *(const short8*)(&Bs[cur][sb[2]]);
        fb[3] = *(const short8*)(&Bs[cur][sb[3]]);
        // cluster 2: 8 MFMAs on fb[2..3]
        __builtin_amdgcn_s_setprio(1);
#pragma unroll
        for (int fi = 0; fi < 4; ++fi) {
            acc[fi][2] = __builtin_amdgcn_mfma_f32_16x16x32_bf16(
                    fa[fi], fb[2], acc[fi][2], 0, 0, 0);
            acc[fi][3] = __builtin_amdgcn_mfma_f32_16x16x32_bf16(
                    fa[fi], fb[3], acc[fi][3], 0, 0, 0);
        }
        __builtin_amdgcn_s_setprio(0);
        cur = (cur == 2) ? 0 : cur + 1;
    }

    int rbase = (lane >> 4) * 4;
    int cbase = n0 + wn * 64 + (lane & 15);
#pragma unroll
    for (int fi = 0; fi < 4; ++fi) {
        int r0 = m0 + wm * 64 + fi * 16 + rbase;
#pragma unroll
        for (int fj = 0; fj < 4; ++fj) {
            int col = cbase + fj * 16;
            if (MODE == 0) {
                int p = col >> 9, d = col & 511;
                float bv_ = bias[col];
                float w0 = acc[fi][fj][0] + bv_;
                float w1 = acc[fi][fj][1] + bv_;
                float w2 = acc[fi][fj][2] + bv_;
                float w3 = acc[fi][fj][3] + bv_;
                size_t tb = ((size_t)(r0 >> 11) * ND + d) * NS + (r0 & 2047);
                if (p == 0) {                      // q
                    u16* q = (u16*)(pb + OFF_QB);
                    q[(size_t)(r0 + 0) * ND + d] = f2bf(w0);
                    q[(size_t)(r0 + 1) * ND + d] = f2bf(w1);
                    q[(size_t)(r0 + 2) * ND + d] = f2bf(w2);
                    q[(size_t)(r0 + 3) * ND + d] = f2bf(w3);
                } else if (p == 1) {               // k scaled: row-major + transposed
                    float s0 = w0 * KSCALE, s1 = w1 * KSCALE;
                    float s2 = w2 * KSCALE, s3 = w3 * KSCALE;
                    u16* kbuf = (u16*)(pb + OFF_KB);
                    kbuf[(size_t)(r0 + 0) * ND + d] = f2bf(s0);
                    kbuf[(size_t)(r0 + 1) * ND + d] = f2bf(s1);
                    kbuf[(size_t)(r0 + 2) * ND + d] = f2bf(s2);
                    kbuf[(size_t)(r0 + 3) * ND + d] = f2bf(s3);
                    uint2 wv = make_uint2((u32)f2bf(s0) | ((u32)f2bf(s1) << 16),
                                          (u32)f2bf(s2) | ((u32)f2bf(s3) << 16));
                    *(uint2*)((u16*)(pb + OFF_KT) + tb) = wv;
                } else if (p == 2) {               // v
                    uint2 wv = make_uint2((u32)f2bf(w0) | ((u32)f2bf(w1) << 16),
                                          (u32)f2bf(w2) | ((u32)f2bf(w3) << 16));
                    *(uint2*)((u16*)(pb + OFF_VT) + tb) = wv;
                } else if (p == 3) {               // o: sigmoid
                    float s0 = 1.0f / (1.0f + __expf(-w0));
                    float s1 = 1.0f / (1.0f + __expf(-w1));
                    float s2 = 1.0f / (1.0f + __expf(-w2));
                    float s3 = 1.0f / (1.0f + __expf(-w3));
                    uint2 wv = make_uint2((u32)f2bf(s0) | ((u32)f2bf(s1) << 16),
                                          (u32)f2bf(s2) | ((u32)f2bf(s3) << 16));
                    *(uint2*)((u16*)(pb + OFF_OT) + tb) = wv;
                } else {                           // it: bf16 transposed
                    uint2 wv = make_uint2((u32)f2bf(w0) | ((u32)f2bf(w1) << 16),
                                          (u32)f2bf(w2) | ((u32)f2bf(w3) << 16));
                    *(uint2*)((u16*)(pb + OFF_IT) + tb) = wv;
                }
            } else if (MODE == 3) {                // ft only: f32 transposed
                int d = col;
                float bv_ = bias[col];
                float w0 = acc[fi][fj][0] + bv_;
                float w1 = acc[fi][fj][1] + bv_;
                float w2 = acc[fi][fj][2] + bv_;
                float w3 = acc[fi][fj][3] + bv_;
                size_t tb = ((size_t)(r0 >> 11) * ND + d) * NS + (r0 & 2047);
                *(float4*)((float*)(pb + OFF_FT) + tb) = make_float4(w0, w1, w2, w3);
            } else {
#pragma unroll
                for (int r = 0; r < 4; ++r) {
                    int row = r0 + r;
                    float v = acc[fi][fj][r];
                    if (MODE == 1) {
                        float val = v + bias[col];
                        val = 0.5f * val * (1.0f + erff(val * 0.70710678118654752f));
                        outh[(size_t)row * N + col] = f2bf(val);
                    } else {
                        float val = v + bias[col] + resid[(size_t)row * ND + col];
                        outf[(size_t)row * ND + col] = val;
                    }
                }
            }
        }
    }
}

extern "C" void kernel_launch(void* const* d_in, const int* in_sizes, int n_in,
                              void* d_out, int out_size, void* d_ws, size_t ws_size,
                              hipStream_t stream) {
    const float* x    = (const float*)d_in[0];
    const float* ln1g = (const float*)d_in[1];
    const float* ln1b = (const float*)d_in[2];
    const float* ln2g = (const float*)d_in[3];
    const float* ln2b = (const float*)d_in[4];
    const float* Wq = (const float*)d_in[5];
    const float* bq = (const float*)d_in[6];
    const float* Wk = (const float*)d_in[7];
    const float* bk = (const float*)d_in[8];
    const float* Wv = (const float*)d_in[9];
    const float* bv = (const float*)d_in[10];
    const float* Wi = (const float*)d_in[11];
    const float* bi = (const float*)d_in[12];
    const float* Wf = (const float*)d_in[13];
    const float* bfp = (const float*)d_in[14];
    const float* Wo = (const float*)d_in[15];
    const float* bo = (const float*)d_in[16];
    const float* W1 = (const float*)d_in[17];
    const float* b1 = (const float*)d_in[18];
    const float* W2 = (const float*)d_in[19];
    const float* b2 = (const float*)d_in[20];
    float* out = (float*)d_out;

    char* ws = (char*)d_ws;
    size_t off = 0;
    u16* W5T    = (u16*)(ws + off); off += (size_t)2560 * 512 * 2;   // 2.6 MB
    u16* WcT    = (u16*)(ws + off); off += (size_t)512 * 1536 * 2;   // 1.5 MB
    u16* W1T    = (u16*)(ws + off); off += (size_t)2048 * 512 * 2;   // 2 MB
    u16* W2T    = (u16*)(ws + off); off += (size_t)512 * 2048 * 2;   // 2 MB
    float* ball = (float*)(ws + off); off += 3072 * 4;
    off = (off + 255) & ~(size_t)255;
    char* U = ws + off;
    u16*   Acorr = (u16*)(U + OFF_AC);
    u16*   Hbuf  = (u16*)(U + OFF_AC);          // bf16 H aliases Acorr
    u16* ffnin = (u16*)U;                       // aliases dead Qbf
    u16* Gbuf  = (u16*)(U + OFF_KB);            // aliases dead Kbf/KT/VT/OT
    u16* A1g   = (u16*)(U + OFF_KB);            // aliases Kbf AFTER gqk
    u16* A2g   = (u16*)(U + OFF_X);
    u16* Ubg   = (u16*)(U + OFF_UB);
    float* gamg = (float*)(U + OFF_GA);
    size_t needed = (size_t)(U - ws) + OFF_END;
    if (ws_size < needed) return;

    // 1. fused prep + LN1: 16396 + 4096 blocks
    prep_kernel<<<20492, 256, 0, stream>>>(
            Wq, Wk, Wv, Wo, Wi, Wf, W1, W2,
            bq, bk, bv, bo, bi, bfp, x, ln1g, ln1b,
            W5T, WcT, W1T, W2T, ball, Acorr);

    // 2a. qkvo+it GEMM: N=2560, K=512, XCD-swizzled 1D grid (nx=20)
    gemm_kernel<0><<<20 * 64, 512, 0, stream>>>(
            Acorr, W5T, NM, 2560, 512, 1024, 512, 1 << 30, 20, ball,
            U, nullptr, nullptr, nullptr);
    // 2b. ft split-precision GEMM: N=512, K=1536, A wraps at 1024 (nx=4)
    gemm_kernel<3><<<4 * 64, 512, 0, stream>>>(
            Acorr, WcT, NM, 512, 1536, 1024, 1536, 1024, 4, ball + 2560,
            U, nullptr, nullptr, nullptr);

    // 3a. fused G diag + off-diag
    gqk2_kernel<<<NB * NCH + NB * NCH2, 256, 0, stream>>>(
            (const u16*)(U + OFF_QB), (const u16*)(U + OFF_KB),
            (u16*)(U + OFF_G), (u16*)(U + OFF_GO));

    // 3b. gate scan, CL2=128 (IT bf16; A1 overwrites dead KB)
    gates_kernel<<<NB * 32 * 8, 128, 0, stream>>>(
            (const u16*)(U + OFF_IT), (const float*)(U + OFF_FT),
            (const u16*)(U + OFF_VT), A1g, A2g, Ubg, gamg);

    // 3c. chunked recurrence, CL2=128, bf16 H
    recur_kernel<<<NB * 32, 512, 0, stream>>>(
            (const u16*)(U + OFF_QB), (const u16*)(U + OFF_KT),
            (const u16*)(U + OFF_G), (const u16*)(U + OFF_GO),
            A1g, A2g, Ubg, gamg, (const u16*)(U + OFF_OT), Hbuf);

    // 4. residual + LN2 (bf16 h)
    resid_ln2_kernel<<<NM / 4, 256, 0, stream>>>(x, Hbuf, ln2g, ln2b, out, ffnin);

    // 5. FFN1 (nx=16)
    gemm_kernel<1><<<16 * 64, 512, 0, stream>>>(
            ffnin, W1T, NM, 2048, 512, 512, 512, 1 << 30, 16, b1,
            nullptr, nullptr, Gbuf, nullptr);

    // 6. FFN2 (nx=4)
    gemm_kernel<2><<<4 * 64, 512, 0, stream>>>(
            Gbuf, W2T, NM, 512, 2048, 2048, 2048, 1 << 30, 4, b2,
            nullptr, out, nullptr, out);

    (void)in_sizes; (void)n_in; (void)out_size; (void)ws_size;
}

// Round 22
// 457.093 us; speedup vs baseline: 1.0662x; 1.0662x over previous
//
#include <hip/hip_runtime.h>
#include <hip/hip_bf16.h>
#include <cstdint>

typedef unsigned short u16;
typedef unsigned int u32;
typedef __attribute__((ext_vector_type(8))) short short8;
typedef __attribute__((ext_vector_type(4))) float f32x4;

#define NB 8
#define NS 2048
#define ND 512
#define NM (NB * NS)            // 16384 rows
#define CL 64                   // tril-G tile length
#define NCH (NS / CL)           // 32 tril tiles
#define CL2 128                 // recurrence chunk length
#define NCH2 (NS / CL2)         // 16 chunks
static constexpr size_t BSDn = (size_t)NM * ND;   // 8388608 elems
#define KSCALE 0.044194173824159216f              // 1/sqrt(512)

// U-region byte offsets
#define OFF_QB ((size_t)0)            // Qbf  [b,t,d] bf16 16MB
#define OFF_KB (BSDn * 2)             // Kbf  [b,t,d] (gqk); then A1 tiles (gates)
#define OFF_KT (BSDn * 4)             // KT   [b,d,t] bf16 (scaled) 16MB
#define OFF_VT (BSDn * 6)             // VT   [b,d,t] bf16 16MB
#define OFF_OT (BSDn * 8)             // OT   [b,d,t] bf16 (sigmoid) 16MB
#define OFF_IT (BSDn * 10)            // IT   [b,d,t] bf16 16MB (dead after gates)
#define OFF_FT (BSDn * 14)            // FT   [b,d,t] f32 32MB (dead after gates)
#define OFF_G  (BSDn * 18)            // Gd   [b][32][64][64] bf16 2MB (tril diag)
#define OFF_GO (BSDn * 18 + ((size_t)2 << 20))   // Goff [b][16][64][64] 1MB
#define OFF_AC (BSDn * 18 + ((size_t)3 << 20))   // Acorr (32MB) / Hbuf(bf16) alias
#define OFF_X  (OFF_AC + ((size_t)32 << 20))     // A2 (16MB)
#define OFF_UB (OFF_X + ((size_t)16 << 20))      // Ub (16MB)
#define OFF_GA (OFF_UB + ((size_t)16 << 20))     // gam (f32)
#define OFF_END (OFF_GA + ((size_t)1 << 20))

typedef __attribute__((address_space(1))) const u32 gas_u32;
typedef __attribute__((address_space(3))) u32 las_u32;

__device__ __forceinline__ u16 f2bf(float f) {
    u32 i = __builtin_bit_cast(u32, f);
    u32 r = i + 0x7FFFu + ((i >> 16) & 1u);
    return (u16)(r >> 16);
}
__device__ __forceinline__ float bf2f(u16 h) {
    return __builtin_bit_cast(float, (u32)h << 16);
}
__device__ __forceinline__ float bflo(u32 w) {
    return __builtin_bit_cast(float, w << 16);
}
__device__ __forceinline__ float bfhi(u32 w) {
    return __builtin_bit_cast(float, w & 0xffff0000u);
}

// LDS-only barrier: drains own LDS ops + s_barrier; global prefetch loads
// stay in flight across the barrier.
__device__ __forceinline__ void lds_barrier() {
    __builtin_amdgcn_sched_barrier(0);
    asm volatile("s_waitcnt lgkmcnt(0)" ::: "memory");
    __builtin_amdgcn_s_barrier();
    __builtin_amdgcn_sched_barrier(0);
}

// ---------------- fused prep: W5T, WcT (ft), W1T, W2T, bias concat, LN1
__global__ __launch_bounds__(256) void prep_kernel(
        const float* __restrict__ Wq, const float* __restrict__ Wk,
        const float* __restrict__ Wv, const float* __restrict__ Wo,
        const float* __restrict__ Wi, const float* __restrict__ Wf,
        const float* __restrict__ W1, const float* __restrict__ W2,
        const float* __restrict__ bq, const float* __restrict__ bk,
        const float* __restrict__ bv, const float* __restrict__ bo,
        const float* __restrict__ bi, const float* __restrict__ bf_,
        const float* __restrict__ x, const float* __restrict__ ln1g,
        const float* __restrict__ ln1b,
        u16* __restrict__ W5T, u16* __restrict__ WcT,
        u16* __restrict__ W1T, u16* __restrict__ W2T,
        float* __restrict__ ball, u16* __restrict__ nout) {
    int blk = blockIdx.x, tid = threadIdx.x;
    if (blk < 5120) {                          // W5T [2560][512]: q,k,v,o,it
        int idx = blk * 256 + tid;
        int n = idx >> 9, k = idx & 511;
        int p = n >> 9, d = n & 511;
        const float* Wp = (p == 0) ? Wq : (p == 1) ? Wk : (p == 2) ? Wv
                        : (p == 3) ? Wo : Wi;
        W5T[idx] = f2bf(Wp[(size_t)k * 512 + d]);
    } else if (blk < 8192) {                   // WcT [512][1536] = [WH|WH|WL] (ft)
        int idx = (blk - 5120) * 256 + tid;
        int n = idx / 1536, k = idx - n * 1536;
        int d = n;
        u16 o;
        if (k < 1024) {
            o = f2bf(Wf[(size_t)(k & 511) * 512 + d]);
        } else {
            float w = Wf[(size_t)(k - 1024) * 512 + d];
            o = f2bf(w - bf2f(f2bf(w)));
        }
        WcT[idx] = o;
    } else if (blk < 12288) {                  // W1T [2048][512]
        int idx = (blk - 8192) * 256 + tid;
        int n = idx >> 9, k = idx & 511;
        W1T[idx] = f2bf(W1[(size_t)k * 2048 + n]);
    } else if (blk < 16384) {                  // W2T [512][2048]
        int idx = (blk - 12288) * 256 + tid;
        int n = idx >> 11, k = idx & 2047;
        W2T[idx] = f2bf(W2[(size_t)k * 512 + n]);
    } else if (blk < 16396) {                  // bias concat [q,k,v,o,it,ft]
        int idx = (blk - 16384) * 256 + tid;
        if (idx < 3072) {
            int p = idx >> 9, d = idx & 511;
            float v;
            switch (p) {
                case 0: v = bq[d]; break;
                case 1: v = bk[d]; break;
                case 2: v = bv[d]; break;
                case 3: v = bo[d]; break;
                case 4: v = bi[d]; break;
                default: v = bf_[d]; break;
            }
            ball[idx] = v;
        }
    } else {                                   // LN1: 4 rows per block
        int wave = tid >> 6, lane = tid & 63;
        size_t row = (size_t)(blk - 16396) * 4 + wave;
        const float* xr = x + row * ND + lane * 8;
        float4 a0 = *(const float4*)xr;
        float4 a1 = *(const float4*)(xr + 4);
        float xs[8] = {a0.x, a0.y, a0.z, a0.w, a1.x, a1.y, a1.z, a1.w};
        float s = 0.f;
#pragma unroll
        for (int u = 0; u < 8; ++u) s += xs[u];
#pragma unroll
        for (int off = 32; off; off >>= 1) s += __shfl_xor(s, off);
        float mu = s * (1.0f / ND);
        float ss = 0.f;
#pragma unroll
        for (int u = 0; u < 8; ++u) { xs[u] -= mu; ss += xs[u] * xs[u]; }
#pragma unroll
        for (int off = 32; off; off >>= 1) ss += __shfl_xor(ss, off);
        float rs = rsqrtf(ss * (1.0f / ND) + 1e-5f);
        const float* gp = ln1g + lane * 8;
        const float* bp = ln1b + lane * 8;
        float4 g0 = *(const float4*)gp, g1 = *(const float4*)(gp + 4);
        float4 c0 = *(const float4*)bp, c1 = *(const float4*)(bp + 4);
        float gg[8] = {g0.x, g0.y, g0.z, g0.w, g1.x, g1.y, g1.z, g1.w};
        float cc[8] = {c0.x, c0.y, c0.z, c0.w, c1.x, c1.y, c1.z, c1.w};
        u32 owh[4], owl[4];
#pragma unroll
        for (int u = 0; u < 4; ++u) {
            float y0 = xs[2 * u] * rs * gg[2 * u] + cc[2 * u];
            float y1 = xs[2 * u + 1] * rs * gg[2 * u + 1] + cc[2 * u + 1];
            u16 h0 = f2bf(y0), h1 = f2bf(y1);
            u16 l0 = f2bf(y0 - bf2f(h0)), l1 = f2bf(y1 - bf2f(h1));
            owh[u] = (u32)h0 | ((u32)h1 << 16);
            owl[u] = (u32)l0 | ((u32)l1 << 16);
        }
        u16* rb = nout + row * 1024;
        *(uint4*)(rb + lane * 8) = make_uint4(owh[0], owh[1], owh[2], owh[3]);
        *(uint4*)(rb + 512 + lane * 8) = make_uint4(owl[0], owl[1], owl[2], owl[3]);
    }
}

// ---------------- residual add + LN2 (h in bf16)
__global__ __launch_bounds__(256) void resid_ln2_kernel(const float* __restrict__ x,
        const u16* __restrict__ h, const float* __restrict__ g,
        const float* __restrict__ bb, float* __restrict__ outb,
        u16* __restrict__ fin) {
    int wave = threadIdx.x >> 6, lane = threadIdx.x & 63;
    size_t row = (size_t)blockIdx.x * 4 + wave;
    const float* xr = x + row * ND + lane * 8;
    float4 a0 = *(const float4*)xr;
    float4 a1 = *(const float4*)(xr + 4);
    uint4 hv = *(const uint4*)(h + row * ND + lane * 8);
    float xs[8] = {a0.x + bflo(hv.x), a0.y + bfhi(hv.x),
                   a0.z + bflo(hv.y), a0.w + bfhi(hv.y),
                   a1.x + bflo(hv.z), a1.y + bfhi(hv.z),
                   a1.z + bflo(hv.w), a1.w + bfhi(hv.w)};
    float* orow = outb + row * ND + lane * 8;
    *(float4*)orow = make_float4(xs[0], xs[1], xs[2], xs[3]);
    *(float4*)(orow + 4) = make_float4(xs[4], xs[5], xs[6], xs[7]);
    float s = 0.f;
#pragma unroll
    for (int u = 0; u < 8; ++u) s += xs[u];
#pragma unroll
    for (int off = 32; off; off >>= 1) s += __shfl_xor(s, off);
    float mu = s * (1.0f / ND);
    float ss = 0.f;
#pragma unroll
    for (int u = 0; u < 8; ++u) { xs[u] -= mu; ss += xs[u] * xs[u]; }
#pragma unroll
    for (int off = 32; off; off >>= 1) ss += __shfl_xor(ss, off);
    float rs = rsqrtf(ss * (1.0f / ND) + 1e-5f);
    const float* gp = g + lane * 8;
    const float* bp = bb + lane * 8;
    float4 g0 = *(const float4*)gp, g1 = *(const float4*)(gp + 4);
    float4 c0 = *(const float4*)bp, c1 = *(const float4*)(bp + 4);
    float gg[8] = {g0.x, g0.y, g0.z, g0.w, g1.x, g1.y, g1.z, g1.w};
    float cc[8] = {c0.x, c0.y, c0.z, c0.w, c1.x, c1.y, c1.z, c1.w};
    u32 ow[4];
#pragma unroll
    for (int u = 0; u < 4; ++u) {
        float y0 = xs[2 * u] * rs * gg[2 * u] + cc[2 * u];
        float y1 = xs[2 * u + 1] * rs * gg[2 * u + 1] + cc[2 * u + 1];
        ow[u] = (u32)f2bf(y0) | ((u32)f2bf(y1) << 16);
    }
    *(uint4*)(fin + row * ND + lane * 8) = make_uint4(ow[0], ow[1], ow[2], ow[3]);
}

// ---------------- fused G kernel: diag (tril, 256 blocks) + off-diag (128 blocks)
__global__ __launch_bounds__(256) void gqk2_kernel(
        const u16* __restrict__ Qb, const u16* __restrict__ Kb,
        u16* __restrict__ Gd, u16* __restrict__ Go) {
    __shared__ u16 Qs[64][520];
    __shared__ u16 Ks[64][520];
    int tid = threadIdx.x;
    int w = tid >> 6, lane = tid & 63;
    int blk = blockIdx.x;
    int b, t0q, t0k;
    bool masked;
    u16* gout;
    if (blk < 256) {
        b = blk >> 5;
        int c = blk & 31;
        t0q = t0k = c * CL;
        masked = true;
        gout = Gd + (size_t)(b * NCH + c) * CL * CL;
    } else {
        int z = blk - 256;
        b = z >> 4;
        int c = z & 15;
        t0q = c * CL2 + 64;
        t0k = c * CL2;
        masked = false;
        gout = Go + (size_t)(b * NCH2 + c) * CL * CL;
    }
    {
        int row = tid >> 2, cb = (tid & 3) * 128;
        const u16* qsrc = Qb + ((size_t)b * NS + t0q + row) * ND + cb;
        const u16* ksrc = Kb + ((size_t)b * NS + t0k + row) * ND + cb;
#pragma unroll
        for (int u = 0; u < 16; ++u) {
            *(short8*)&Qs[row][cb + u * 8] = *(const short8*)(qsrc + u * 8);
            *(short8*)&Ks[row][cb + u * 8] = *(const short8*)(ksrc + u * 8);
        }
    }
    __syncthreads();
    int qw = lane & 15, kg = lane >> 4;
    f32x4 ga[4];
#pragma unroll
    for (int ns = 0; ns < 4; ++ns) ga[ns] = (f32x4){0.f, 0.f, 0.f, 0.f};
    for (int kb = 0; kb < 16; ++kb) {
        short8 aq = *(const short8*)&Qs[(w << 4) + qw][kb * 32 + (kg << 3)];
#pragma unroll
        for (int ns = 0; ns < 4; ++ns) {
            short8 bk = *(const short8*)&Ks[(ns << 4) + qw][kb * 32 + (kg << 3)];
            ga[ns] = __builtin_amdgcn_mfma_f32_16x16x32_bf16(aq, bk, ga[ns], 0, 0, 0);
        }
    }
#pragma unroll
    for (int ns = 0; ns < 4; ++ns) {
#pragma unroll
        for (int rg = 0; rg < 4; ++rg) {
            int t = (w << 4) + (kg << 2) + rg;
            int s = (ns << 4) + qw;
            gout[t * CL + s] = (!masked || s <= t) ? f2bf(ga[ns][rg]) : (u16)0;
        }
    }
}

// ---------------- gates kernel, CL2=128 (IT bf16)
__global__ __launch_bounds__(128) void gates_kernel(
        const u16* __restrict__ IT, const float* __restrict__ FT,
        const u16* __restrict__ VT,
        u16* __restrict__ A1g, u16* __restrict__ A2g,
        u16* __restrict__ Ubg, float* __restrict__ gamg) {
    int w = threadIdx.x >> 6, lane = threadIdx.x & 63;
    int rp = blockIdx.x & 7;
    int bl = blockIdx.x >> 3;            // b*32 + isl
    int b = bl >> 5, isl = bl & 31;
    int il = rp * 2 + w;                 // 0..15
    int i = (isl << 4) + il;
    size_t rowb = ((size_t)b * ND + i) * NS;
    size_t tb = (size_t)bl * 32768 + il * 128;   // + c*2048 + t
    float mo = 0.f;
    for (int c = 0; c < NCH2; ++c) {
        size_t g0 = rowb + c * CL2 + lane;
        float ft0 = FT[g0], it0 = bf2f(IT[g0]), v0 = bf2f(VT[g0]);
        float ft1 = FT[g0 + 64], it1 = bf2f(IT[g0 + 64]), v1 = bf2f(VT[g0 + 64]);
        float bs0 = ft0;
#pragma unroll
        for (int o = 1; o < 64; o <<= 1) {
            float nv = __shfl_up(bs0, o);
            if (lane >= o) bs0 += nv;
        }
        float e0 = it0 - bs0;
        float M0 = e0;
#pragma unroll
        for (int o = 1; o < 64; o <<= 1) {
            float nv = __shfl_up(M0, o);
            if (lane >= o) M0 = fmaxf(M0, nv);
        }
        M0 = fmaxf(M0, mo);
        float M0t = __shfl(M0, 63);
        float bs0t = __shfl(bs0, 63);
        float bs1 = ft1;
#pragma unroll
        for (int o = 1; o < 64; o <<= 1) {
            float nv = __shfl_up(bs1, o);
            if (lane >= o) bs1 += nv;
        }
        bs1 += bs0t;
        float e1 = it1 - bs1;
        float M1 = e1;
#pragma unroll
        for (int o = 1; o < 64; o <<= 1) {
            float nv = __shfl_up(M1, o);
            if (lane >= o) M1 = fmaxf(M1, nv);
        }
        M1 = fmaxf(M1, M0t);
        float E = __shfl(M1, 63);
        float bst = __shfl(bs1, 63);
        size_t oofs = tb + (size_t)c * 2048 + lane;
        Ubg[oofs] = f2bf(__expf(e0 - E) * v0);
        A1g[oofs] = f2bf(__expf(mo - M0));
        A2g[oofs] = f2bf(__expf(fminf(E - M0, 80.f)));
        Ubg[oofs + 64] = f2bf(__expf(e1 - E) * v1);
        A1g[oofs + 64] = f2bf(__expf(mo - M1));
        A2g[oofs + 64] = f2bf(__expf(fminf(E - M1, 80.f)));
        if (lane == 0) gamg[((size_t)bl * NCH2 + c) * 16 + il] = __expf(mo - E);
        mo = bst + E;
    }
}

// ---------------- chunked mLSTM recurrence v6 (frozen at ~141us)
__global__ __launch_bounds__(512, 2) void recur_kernel(
        const u16* __restrict__ Qb, const u16* __restrict__ KT,
        const u16* __restrict__ Gd, const u16* __restrict__ Go,
        const u16* __restrict__ A1g, const u16* __restrict__ A2g,
        const u16* __restrict__ Ubg, const float* __restrict__ gamg,
        const u16* __restrict__ OT, u16* __restrict__ H) {
    __shared__ u16 Chi[2][16][520];
    __shared__ u16 Ubl[2][16][136];
    __shared__ u16 A1l[2][16][136];
    __shared__ u16 A2l[2][16][136];
    __shared__ float gaml[2][16];
    int tid = threadIdx.x;
    int w = tid >> 6, lane = tid & 63;
    int hb = w >> 2, tl16 = w & 3;
    int b = blockIdx.x & 7;              // XCD pin
    int isl = blockIdx.x >> 3;
    int i0 = isl << 4;
    int qw = lane & 15, kg = lane >> 4;
    f32x4 cacc[4];
#pragma unroll
    for (int n = 0; n < 4; ++n) cacc[n] = (f32x4){0.f, 0.f, 0.f, 0.f};

    size_t bT = (size_t)b * NS;
    size_t bD = (size_t)b * ND;
    size_t gt2 = (size_t)(b * 32 + isl) * 32768;
    int grow = tid >> 5;
    int gquad = (tid & 31) << 2;

    const u16* qpf = Qb + (bT + w * 16 + qw) * ND + (kg << 3);
    const u16* kpf = KT + (bD + w * 64 + qw) * NS + (kg << 3);
    const u16* gdp = Gd + ((size_t)(b * 32 + hb) * 4096)
                     + (size_t)(tl16 * 16 + qw) * 64 + (kg << 3);
    const u16* gop = Go + ((size_t)(b * 16) * 4096)
                     + (size_t)(tl16 * 16 + qw) * 64 + (kg << 3);
    const u16* ubp = Ubg + gt2 + grow * 128 + gquad;
    const u16* a1p = A1g + gt2 + grow * 128 + gquad;
    const u16* a2p = A2g + gt2 + grow * 128 + gquad;
    const float* gamp = gamg + (size_t)(b * 32 + isl) * (NCH2 * 16) + tid;
    const u16* otp = OT + (bD + i0 + qw) * NS + w * 16 + (kg << 2);

    uint2 nub = make_uint2(0, 0), na1 = make_uint2(0, 0), na2 = make_uint2(0, 0);
    float ngam = 0.f;
    auto issue_gates = [&]() {
        nub = *(const uint2*)ubp; ubp += 2048;
        na1 = *(const uint2*)a1p; a1p += 2048;
        na2 = *(const uint2*)a2p; a2p += 2048;
        if (tid < 16) ngam = *gamp;
        gamp += 16;
    };
    issue_gates();

    for (int c = 0; c < NCH2; ++c) {
        int buf = c & 1;
        int t0 = c * CL2;
        short8 nq[16], nk[16], ngd[2], ngo[2];
#pragma unroll
        for (int kk = 0; kk < 16; ++kk) nq[kk] = *(const short8*)(qpf + kk * 32);
        qpf += CL2 * ND;
#pragma unroll
        for (int kb = 0; kb < 4; ++kb)
#pragma unroll
            for (int n = 0; n < 4; ++n)
                nk[kb * 4 + n] = *(const short8*)(kpf + (size_t)(n << 4) * NS + kb * 32);
        kpf += CL2;
        ngd[0] = *(const short8*)gdp;
        ngd[1] = *(const short8*)(gdp + 32);
        gdp += 2 * 4096;
        if (hb == 1) {
            ngo[0] = *(const short8*)gop;
            ngo[1] = *(const short8*)(gop + 32);
        }
        gop += 4096;
        uint2 cov = *(const uint2*)otp;
        otp += CL2;
        uint2 cub = nub, ca1 = na1, ca2 = na2;
        float cgam = ngam;
        if (c + 1 < NCH2) issue_gates();

        *(uint2*)&Ubl[buf][grow][gquad] = cub;
        *(uint2*)&A1l[buf][grow][gquad] = ca1;
        *(uint2*)&A2l[buf][grow][gquad] = ca2;
        if (tid < 16) gaml[buf][tid] = cgam;
#pragma unroll
        for (int n = 0; n < 4; ++n) {
            int j = (w << 6) + (n << 4) + qw;
#pragma unroll
            for (int rg = 0; rg < 4; ++rg)
                Chi[buf][(kg << 2) + rg][j] = f2bf(cacc[n][rg]);
        }
        lds_barrier();

        f32x4 qc0 = (f32x4){0.f, 0.f, 0.f, 0.f};
        f32x4 qc1 = (f32x4){0.f, 0.f, 0.f, 0.f};
#pragma unroll
        for (int kk = 0; kk < 8; ++kk) {
            short8 b0 = *(const short8*)&Chi[buf][qw][(2 * kk) * 32 + (kg << 3)];
            short8 b1_ = *(const short8*)&Chi[buf][qw][(2 * kk + 1) * 32 + (kg << 3)];
            qc0 = __builtin_amdgcn_mfma_f32_16x16x32_bf16(nq[2 * kk], b0, qc0, 0, 0, 0);
            qc1 = __builtin_amdgcn_mfma_f32_16x16x32_bf16(nq[2 * kk + 1], b1_, qc1, 0, 0, 0);
        }
        f32x4 pin = (f32x4){0.f, 0.f, 0.f, 0.f};
        if (hb == 0) {
#pragma unroll
            for (int kb = 0; kb < 2; ++kb) {
                short8 bu = *(const short8*)&Ubl[buf][qw][kb * 32 + (kg << 3)];
                pin = __builtin_amdgcn_mfma_f32_16x16x32_bf16(ngd[kb], bu, pin, 0, 0, 0);
            }
        } else {
#pragma unroll
            for (int kb = 0; kb < 2; ++kb) {
                short8 bu = *(const short8*)&Ubl[buf][qw][kb * 32 + (kg << 3)];
                pin = __builtin_amdgcn_mfma_f32_16x16x32_bf16(ngo[kb], bu, pin, 0, 0, 0);
            }
#pragma unroll
            for (int kb = 0; kb < 2; ++kb) {
                short8 bu = *(const short8*)&Ubl[buf][qw][64 + kb * 32 + (kg << 3)];
                pin = __builtin_amdgcn_mfma_f32_16x16x32_bf16(ngd[kb], bu, pin, 0, 0, 0);
            }
        }
        {
            float g[4];
#pragma unroll
            for (int rg = 0; rg < 4; ++rg) g[rg] = gaml[buf][(kg << 2) + rg];
#pragma unroll
            for (int n = 0; n < 4; ++n) {
#pragma unroll
                for (int rg = 0; rg < 4; ++rg) cacc[n][rg] *= g[rg];
            }
#pragma unroll
            for (int kb = 0; kb < 4; ++kb) {
                short8 au = *(const short8*)&Ubl[buf][qw][kb * 32 + (kg << 3)];
#pragma unroll
                for (int n = 0; n < 4; ++n)
                    cacc[n] = __builtin_amdgcn_mfma_f32_16x16x32_bf16(
                            au, nk[kb * 4 + n], cacc[n], 0, 0, 0);
            }
        }
        {
            float ov[4];
            ov[0] = bf2f((u16)(cov.x & 0xffff));
            ov[1] = bf2f((u16)(cov.x >> 16));
            ov[2] = bf2f((u16)(cov.y & 0xffff));
            ov[3] = bf2f((u16)(cov.y >> 16));
#pragma unroll
            for (int rg = 0; rg < 4; ++rg) {
                int tl = w * 16 + (kg << 2) + rg;
                float a1v = bf2f(A1l[buf][qw][tl]);
                float a2v = bf2f(A2l[buf][qw][tl]);
                float qc = qc0[rg] + qc1[rg];
                H[(bT + t0 + tl) * ND + i0 + qw] =
                        f2bf(ov[rg] * (a1v * qc + a2v * pin[rg]));
            }
        }
    }
}

// ---------------- bf16 MFMA GEMM: 256x128 tile, 8 waves, 3-buffer LDS,
// counted vmcnt(3), raw barriers, XCD-chunked block swizzle (ny=64 fixed).
// (round-20 inner loop: contiguous fragment reads, single MFMA block)
// MODE 0: qkvo+it (N=2560)   MODE 3: ft (N=512)
// MODE 1: ffn1 gelu bf16     MODE 2: ffn2 + resid f32
template <int MODE>
__global__ __launch_bounds__(512) void gemm_kernel(
        const u16* __restrict__ A, const u16* __restrict__ BT,
        int M, int N, int K, int lda, int ldb, int kwrap, int nx,
        const float* __restrict__ bias,
        char* __restrict__ pb,
        float* __restrict__ outf, u16* __restrict__ outh,
        const float* __restrict__ resid) {
    __shared__ u16 As[3][256 * 32];
    __shared__ u16 Bs[3][128 * 32];
    int tid = threadIdx.x;
    int wave = tid >> 6, lane = tid & 63;
    int wm = wave >> 1, wn = wave & 1;     // 4 x 2 wave grid
    // XCD-chunked swizzle: each XCD owns 8 consecutive A-panels (ny=64, 8 XCDs)
    int xcd = blockIdx.x & 7;
    int slot = blockIdx.x >> 3;
    int by = xcd * 8 + slot / nx;
    int bx = slot - (slot / nx) * nx;
    int m0 = by * 256;
    int n0 = bx * 128;

    f32x4 acc[4][4];
#pragma unroll
    for (int fi = 0; fi < 4; ++fi)
#pragma unroll
        for (int fj = 0; fj < 4; ++fj)
            acc[fi][fj] = (f32x4){0.f, 0.f, 0.f, 0.f};

    // staging: A rows [wave*32,+32) via 2 gloads; B rows [wave*16,+16) via 1.
    int srow = lane >> 2;
    int slotl = lane & 3;
    int rA0 = wave * 32 + srow;
    int gsA0 = (slotl ^ ((rA0 >> 1) & 3)) << 3;
    int gsA1 = (slotl ^ (((rA0 + 16) >> 1) & 3)) << 3;
    int rB = wave * 16 + srow;
    int gsB = (slotl ^ ((rB >> 1) & 3)) << 3;
    const u16* Ag0 = A + (size_t)(m0 + rA0) * lda + gsA0;
    const u16* Ag1 = A + (size_t)(m0 + rA0 + 16) * lda + gsA1;
    const u16* Bg = BT + (size_t)(n0 + rB) * ldb + gsB;
    int wlA0 = wave * 32 * 32;
    int wlA1 = wlA0 + 16 * 32;
    int wlB = wave * 16 * 32;

    int fr = lane & 15, kb = lane >> 4;
    int sa[4], sb[4];
#pragma unroll
    for (int f = 0; f < 4; ++f) {
        int ra = wm * 64 + f * 16 + fr;
        int rb = wn * 64 + f * 16 + fr;
        sa[f] = ra * 32 + ((kb ^ ((ra >> 1) & 3)) << 3);
        sb[f] = rb * 32 + ((kb ^ ((rb >> 1) & 3)) << 3);
    }

    int nk = K >> 5;
    auto STAGE = [&](int t, int bufi) {
        int k0 = t << 5;
        int ak0 = k0 - (k0 >= kwrap ? kwrap : 0);
        __builtin_amdgcn_global_load_lds((gas_u32*)(Ag0 + ak0), (las_u32*)(&As[bufi][wlA0]), 16, 0, 0);
        __builtin_amdgcn_global_load_lds((gas_u32*)(Ag1 + ak0), (las_u32*)(&As[bufi][wlA1]), 16, 0, 0);
        __builtin_amdgcn_global_load_lds((gas_u32*)(Bg + k0), (las_u32*)(&Bs[bufi][wlB]), 16, 0, 0);
    };
    STAGE(0, 0);
    STAGE(1, 1);
    int cur = 0;
#pragma unroll 1
    for (int t = 0; t < nk; ++t) {
        __builtin_amdgcn_sched_barrier(0);
        if (t + 1 < nk) {
            asm volatile("s_waitcnt vmcnt(3)" ::: "memory");
        } else {
            asm volatile("s_waitcnt vmcnt(0)" ::: "memory");
        }
        __builtin_amdgcn_s_barrier();
        __builtin_amdgcn_sched_barrier(0);
        short8 fa[4], fb[4];
#pragma unroll
        for (int f = 0; f < 4; ++f) {
            fa[f] = *(const short8*)(&As[cur][sa[f]]);
            fb[f] = *(const short8*)(&Bs[cur][sb[f]]);
        }
        if (t + 2 < nk) {
            int b2 = cur - 1;
            if (b2 < 0) b2 += 3;
            STAGE(t + 2, b2);
        }
#pragma unroll
        for (int fi = 0; fi < 4; ++fi)
#pragma unroll
            for (int fj = 0; fj < 4; ++fj)
                acc[fi][fj] = __builtin_amdgcn_mfma_f32_16x16x32_bf16(
                        fa[fi], fb[fj], acc[fi][fj], 0, 0, 0);
        cur = (cur == 2) ? 0 : cur + 1;
    }

    int rbase = (lane >> 4) * 4;
    int cbase = n0 + wn * 64 + (lane & 15);
#pragma unroll
    for (int fi = 0; fi < 4; ++fi) {
        int r0 = m0 + wm * 64 + fi * 16 + rbase;
#pragma unroll
        for (int fj = 0; fj < 4; ++fj) {
            int col = cbase + fj * 16;
            if (MODE == 0) {
                int p = col >> 9, d = col & 511;
                float bv_ = bias[col];
                float w0 = acc[fi][fj][0] + bv_;
                float w1 = acc[fi][fj][1] + bv_;
                float w2 = acc[fi][fj][2] + bv_;
                float w3 = acc[fi][fj][3] + bv_;
                size_t tb = ((size_t)(r0 >> 11) * ND + d) * NS + (r0 & 2047);
                if (p == 0) {                      // q
                    u16* q = (u16*)(pb + OFF_QB);
                    q[(size_t)(r0 + 0) * ND + d] = f2bf(w0);
                    q[(size_t)(r0 + 1) * ND + d] = f2bf(w1);
                    q[(size_t)(r0 + 2) * ND + d] = f2bf(w2);
                    q[(size_t)(r0 + 3) * ND + d] = f2bf(w3);
                } else if (p == 1) {               // k scaled: row-major + transposed
                    float s0 = w0 * KSCALE, s1 = w1 * KSCALE;
                    float s2 = w2 * KSCALE, s3 = w3 * KSCALE;
                    u16* kbuf = (u16*)(pb + OFF_KB);
                    kbuf[(size_t)(r0 + 0) * ND + d] = f2bf(s0);
                    kbuf[(size_t)(r0 + 1) * ND + d] = f2bf(s1);
                    kbuf[(size_t)(r0 + 2) * ND + d] = f2bf(s2);
                    kbuf[(size_t)(r0 + 3) * ND + d] = f2bf(s3);
                    uint2 wv = make_uint2((u32)f2bf(s0) | ((u32)f2bf(s1) << 16),
                                          (u32)f2bf(s2) | ((u32)f2bf(s3) << 16));
                    *(uint2*)((u16*)(pb + OFF_KT) + tb) = wv;
                } else if (p == 2) {               // v
                    uint2 wv = make_uint2((u32)f2bf(w0) | ((u32)f2bf(w1) << 16),
                                          (u32)f2bf(w2) | ((u32)f2bf(w3) << 16));
                    *(uint2*)((u16*)(pb + OFF_VT) + tb) = wv;
                } else if (p == 3) {               // o: sigmoid
                    float s0 = 1.0f / (1.0f + __expf(-w0));
                    float s1 = 1.0f / (1.0f + __expf(-w1));
                    float s2 = 1.0f / (1.0f + __expf(-w2));
                    float s3 = 1.0f / (1.0f + __expf(-w3));
                    uint2 wv = make_uint2((u32)f2bf(s0) | ((u32)f2bf(s1) << 16),
                                          (u32)f2bf(s2) | ((u32)f2bf(s3) << 16));
                    *(uint2*)((u16*)(pb + OFF_OT) + tb) = wv;
                } else {                           // it: bf16 transposed
                    uint2 wv = make_uint2((u32)f2bf(w0) | ((u32)f2bf(w1) << 16),
                                          (u32)f2bf(w2) | ((u32)f2bf(w3) << 16));
                    *(uint2*)((u16*)(pb + OFF_IT) + tb) = wv;
                }
            } else if (MODE == 3) {                // ft only: f32 transposed
                int d = col;
                float bv_ = bias[col];
                float w0 = acc[fi][fj][0] + bv_;
                float w1 = acc[fi][fj][1] + bv_;
                float w2 = acc[fi][fj][2] + bv_;
                float w3 = acc[fi][fj][3] + bv_;
                size_t tb = ((size_t)(r0 >> 11) * ND + d) * NS + (r0 & 2047);
                *(float4*)((float*)(pb + OFF_FT) + tb) = make_float4(w0, w1, w2, w3);
            } else {
#pragma unroll
                for (int r = 0; r < 4; ++r) {
                    int row = r0 + r;
                    float v = acc[fi][fj][r];
                    if (MODE == 1) {
                        float val = v + bias[col];
                        val = 0.5f * val * (1.0f + erff(val * 0.70710678118654752f));
                        outh[(size_t)row * N + col] = f2bf(val);
                    } else {
                        float val = v + bias[col] + resid[(size_t)row * ND + col];
                        outf[(size_t)row * ND + col] = val;
                    }
                }
            }
        }
    }
}

extern "C" void kernel_launch(void* const* d_in, const int* in_sizes, int n_in,
                              void* d_out, int out_size, void* d_ws, size_t ws_size,
                              hipStream_t stream) {
    const float* x    = (const float*)d_in[0];
    const float* ln1g = (const float*)d_in[1];
    const float* ln1b = (const float*)d_in[2];
    const float* ln2g = (const float*)d_in[3];
    const float* ln2b = (const float*)d_in[4];
    const float* Wq = (const float*)d_in[5];
    const float* bq = (const float*)d_in[6];
    const float* Wk = (const float*)d_in[7];
    const float* bk = (const float*)d_in[8];
    const float* Wv = (const float*)d_in[9];
    const float* bv = (const float*)d_in[10];
    const float* Wi = (const float*)d_in[11];
    const float* bi = (const float*)d_in[12];
    const float* Wf = (const float*)d_in[13];
    const float* bfp = (const float*)d_in[14];
    const float* Wo = (const float*)d_in[15];
    const float* bo = (const float*)d_in[16];
    const float* W1 = (const float*)d_in[17];
    const float* b1 = (const float*)d_in[18];
    const float* W2 = (const float*)d_in[19];
    const float* b2 = (const float*)d_in[20];
    float* out = (float*)d_out;

    char* ws = (char*)d_ws;
    size_t off = 0;
    u16* W5T    = (u16*)(ws + off); off += (size_t)2560 * 512 * 2;   // 2.6 MB
    u16* WcT    = (u16*)(ws + off); off += (size_t)512 * 1536 * 2;   // 1.5 MB
    u16* W1T    = (u16*)(ws + off); off += (size_t)2048 * 512 * 2;   // 2 MB
    u16* W2T    = (u16*)(ws + off); off += (size_t)512 * 2048 * 2;   // 2 MB
    float* ball = (float*)(ws + off); off += 3072 * 4;
    off = (off + 255) & ~(size_t)255;
    char* U = ws + off;
    u16*   Acorr = (u16*)(U + OFF_AC);
    u16*   Hbuf  = (u16*)(U + OFF_AC);          // bf16 H aliases Acorr
    u16* ffnin = (u16*)U;                       // aliases dead Qbf
    u16* Gbuf  = (u16*)(U + OFF_KB);            // aliases dead Kbf/KT/VT/OT
    u16* A1g   = (u16*)(U + OFF_KB);            // aliases Kbf AFTER gqk
    u16* A2g   = (u16*)(U + OFF_X);
    u16* Ubg   = (u16*)(U + OFF_UB);
    float* gamg = (float*)(U + OFF_GA);
    size_t needed = (size_t)(U - ws) + OFF_END;
    if (ws_size < needed) return;

    // 1. fused prep + LN1: 16396 + 4096 blocks
    prep_kernel<<<20492, 256, 0, stream>>>(
            Wq, Wk, Wv, Wo, Wi, Wf, W1, W2,
            bq, bk, bv, bo, bi, bfp, x, ln1g, ln1b,
            W5T, WcT, W1T, W2T, ball, Acorr);

    // 2a. qkvo+it GEMM: N=2560, K=512, XCD-swizzled 1D grid (nx=20)
    gemm_kernel<0><<<20 * 64, 512, 0, stream>>>(
            Acorr, W5T, NM, 2560, 512, 1024, 512, 1 << 30, 20, ball,
            U, nullptr, nullptr, nullptr);
    // 2b. ft split-precision GEMM: N=512, K=1536, A wraps at 1024 (nx=4)
    gemm_kernel<3><<<4 * 64, 512, 0, stream>>>(
            Acorr, WcT, NM, 512, 1536, 1024, 1536, 1024, 4, ball + 2560,
            U, nullptr, nullptr, nullptr);

    // 3a. fused G diag + off-diag
    gqk2_kernel<<<NB * NCH + NB * NCH2, 256, 0, stream>>>(
            (const u16*)(U + OFF_QB), (const u16*)(U + OFF_KB),
            (u16*)(U + OFF_G), (u16*)(U + OFF_GO));

    // 3b. gate scan, CL2=128 (IT bf16; A1 overwrites dead KB)
    gates_kernel<<<NB * 32 * 8, 128, 0, stream>>>(
            (const u16*)(U + OFF_IT), (const float*)(U + OFF_FT),
            (const u16*)(U + OFF_VT), A1g, A2g, Ubg, gamg);

    // 3c. chunked recurrence, CL2=128, bf16 H
    recur_kernel<<<NB * 32, 512, 0, stream>>>(
            (const u16*)(U + OFF_QB), (const u16*)(U + OFF_KT),
            (const u16*)(U + OFF_G), (const u16*)(U + OFF_GO),
            A1g, A2g, Ubg, gamg, (const u16*)(U + OFF_OT), Hbuf);

    // 4. residual + LN2 (bf16 h)
    resid_ln2_kernel<<<NM / 4, 256, 0, stream>>>(x, Hbuf, ln2g, ln2b, out, ffnin);

    // 5. FFN1 (nx=16)
    gemm_kernel<1><<<16 * 64, 512, 0, stream>>>(
            ffnin, W1T, NM, 2048, 512, 512, 512, 1 << 30, 16, b1,
            nullptr, nullptr, Gbuf, nullptr);

    // 6. FFN2 (nx=4)
    gemm_kernel<2><<<4 * 64, 512, 0, stream>>>(
            Gbuf, W2T, NM, 512, 2048, 2048, 2048, 1 << 30, 4, b2,
            nullptr, out, nullptr, out);

    (void)in_sizes; (void)n_in; (void)out_size; (void)ws_size;
}